// Round 17
// baseline (2095.872 us; speedup 1.0000x reference)
//
#include <hip/hip_runtime.h>
#include <stdint.h>

#define NB 256          // batch
#define NH 1024         // hidden
#define NPOSE 135
#define NPPAD 160       // pose padded to 160
#define NSTEPS 143      // 119 encoder + 24 decoder cell steps
#define NDEC 24
#define KTOT 1184       // 1024 (h) + 160 (x padded)
#define LSTR 168        // LDS row stride for x-B chunk
#define NWG 256

typedef __bf16 bf16;
typedef __attribute__((ext_vector_type(8))) __bf16 bf16x8;
typedef __attribute__((ext_vector_type(4))) float f32x4;
typedef __attribute__((ext_vector_type(4))) uint32_t u32x4;

// ---- ws layout (bytes) ----
#define WCAT_OFF 0
#define WCAT_BYTES (4096l * KTOT * 2)
#define WFC_OFF  (WCAT_OFF + WCAT_BYTES)
#define WFC_BYTES (144l * 1024 * 2)
#define X_OFF    (WFC_OFF + WFC_BYTES)
#define X_BYTES  (143l * NB * NPPAD * 2)
#define H_OFF    (X_OFF + X_BYTES)
#define H_BYTES2    (2l * NB * NH * 2)     // fallback: ping-pong
#define H_BYTES144  (144l * NB * NH * 2)   // deep: slot per step -> cacheable
#define BAR_BYTES 16384
// bar ints, one counter per 128B line:
//   cnt[bb][ch] at bar[(bb*8+ch)*32]  (h-chunk ready; 8 producers, +8/step)
//   xcnt[bb]    at bar[(32+bb)*32]    (decoder X ready; +4/out-step)

__device__ __forceinline__ u32x4 llc_ld16(const void* p) {
  u32x4 v;
  asm volatile("global_load_dwordx4 %0, %1, off sc0 sc1"
               : "=v"(v) : "v"(p) : "memory");
  return v;
}
__device__ __forceinline__ uint32_t llc_ld4(const void* p) {   // pipelined flag load
  uint32_t v;
  asm volatile("global_load_dword %0, %1, off sc0 sc1"
               : "=v"(v) : "v"(p) : "memory");
  return v;
}
__device__ __forceinline__ u32x4 g_ld16(const void* p) {   // cached
  u32x4 v;
  asm volatile("global_load_dwordx4 %0, %1, off"
               : "=v"(v) : "v"(p) : "memory");
  return v;
}
__device__ __forceinline__ u32x4 ld16sel(const void* p, bool cached) {
  return cached ? g_ld16(p) : llc_ld16(p);
}
__device__ __forceinline__ void llc_st2(void* p, uint32_t v) {
  asm volatile("global_store_short %0, %1, off sc0 sc1"
               :: "v"(p), "v"(v) : "memory");
}
#define WAIT_VM(n) do { \
    asm volatile("s_waitcnt vmcnt(" #n ")" ::: "memory"); \
    __builtin_amdgcn_sched_barrier(0); } while (0)
// counted wait that degrades to a full drain after a CHK slow path
#define WAIT_VMC(n) do { \
    if (__builtin_expect(drained, 0)) { WAIT_VM(0); } else { WAIT_VM(n); } } while (0)

// Blocking polls force vmcnt(0): only at tail / decoder / slow path.
#define POLL(ptr, tgt) do { \
    while (__hip_atomic_load((ptr), __ATOMIC_RELAXED, __HIP_MEMORY_SCOPE_AGENT) < (tgt)) \
      __builtin_amdgcn_s_sleep(1); \
  } while (0)
#define POLL_ALL8(tgt) do { \
    for (;;) { \
      int v_ = __hip_atomic_load(&bar[(bb * 8 + (lane & 7)) * 32], \
                                 __ATOMIC_RELAXED, __HIP_MEMORY_SCOPE_AGENT); \
      if (__all(v_ >= (tgt))) break; \
      __builtin_amdgcn_s_sleep(1); \
    } } while (0)
#define POLL01(tgt) do { \
    for (;;) { \
      int v_ = __hip_atomic_load(&bar[(bb * 8 + (lane & 1)) * 32], \
                                 __ATOMIC_RELAXED, __HIP_MEMORY_SCOPE_AGENT); \
      if (__all(v_ >= (tgt))) break; \
      __builtin_amdgcn_s_sleep(1); \
    } } while (0)
#define CHKD(fv, ch, tgt) do { \
    while ((int)(fv) < (tgt)) { \
      drained = true; \
      __builtin_amdgcn_s_sleep(1); \
      fv = llc_ld4(&bar[(bb * 8 + (ch)) * 32]); \
      WAIT_VM(0); \
    } } while (0)

__global__ void k_zero(uint32_t* p, int n) {
  int i = blockIdx.x * blockDim.x + threadIdx.x;
  int st = gridDim.x * blockDim.x;
  for (; i < n; i += st) p[i] = 0u;
}

__global__ void k_wcat(const float* __restrict__ Whh, const float* __restrict__ Wih,
                       bf16* __restrict__ W) {
  int n = blockIdx.x;
  for (int kk = threadIdx.x; kk < KTOT; kk += blockDim.x) {
    float v = 0.f;
    if (kk < NH) v = Whh[(size_t)n * NH + kk];
    else if (kk - NH < NPOSE) v = Wih[(size_t)n * NPOSE + (kk - NH)];
    W[(size_t)n * KTOT + kk] = (bf16)v;
  }
}

__global__ void k_wfc(const float* __restrict__ Wfc, bf16* __restrict__ W) {
  int p = blockIdx.x;
  for (int kk = threadIdx.x; kk < NH; kk += blockDim.x) {
    float v = (p < NPOSE) ? Wfc[(size_t)p * NH + kk] : 0.f;
    W[(size_t)p * NH + kk] = (bf16)v;
  }
}

__global__ void k_x(const float* __restrict__ poses, bf16* __restrict__ X) {
  int idx = blockIdx.x;          // t*256 + b, t in [0,120)
  int t = idx >> 8, b = idx & 255;
  int p = threadIdx.x;
  if (p < NPPAD) {
    float v = (p < NPOSE) ? poses[((size_t)b * 144 + t) * NPOSE + p] : 0.f;
    X[(size_t)idx * NPPAD + p] = (bf16)v;
  }
}

__device__ __forceinline__ float sigm(float x) { return 1.f / (1.f + __expf(-x)); }
__device__ __forceinline__ float tanh_(float x) {
  float e = __expf(2.f * x);
  return 1.f - 2.f / (e + 1.f);
}

template <bool DEEP>
__global__ __launch_bounds__(256, 1) void
k_main(const float* __restrict__ poses, const float* __restrict__ bfc,
       const bf16* __restrict__ Wcat, const bf16* __restrict__ Wfcb,
       bf16* __restrict__ X, bf16* __restrict__ H, int* __restrict__ bar,
       float* __restrict__ out) {
  // W staged to LDS once (r7/r9 layout):
  // BldsH[c][r = gate*16 + j][k], 16B-group e stored at slot e ^ (r&15).
  // r17 wave re-tile: wave (bh,jh) = 32 batch rows x (8 j-cols x 4 gates).
  // Each B-frag is read ONCE and feeds TWO MFMAs (A-tiles) -> per-CU LDS
  // B-reads halve (592 -> 296/step); 4 independent acc chains preserved.
  __shared__ bf16 BldsH[8 * 64 * 128];     // 128 KiB
  __shared__ bf16 BldsX[64 * LSTR];        // 21 KiB

  const int tid  = threadIdx.x;
  const int lane = tid & 63;
  const int wv   = tid >> 6;
  const int cl   = lane & 15;
  const int quad = lane >> 4;
  const int bh   = wv & 1;                 // batch half (32 rows)
  const int jh   = wv >> 1;                // j half (8 cols)
  const int L    = blockIdx.x;
  const int jb = (L & 7) * 8 + ((L >> 3) & 7);   // XCD-aware j-block
  const int bb = L >> 6;                          // batch group
  const int b0 = bb * 64;
  const int j0 = jb * 16;
  const int mych = jb >> 3;                       // h-chunk this WG produces
  const bool is_out = ((L & 7) == 7) && (((L >> 3) & 7) < 4);
  const int brow0 = bb * 64 + ((L >> 3) & 7) * 16;

  // ---- one-time B staging (plain loads; compiler-managed waits) ----
  for (int t = tid; t < 8 * 64 * 16; t += 256) {
    int c = t >> 10, rem = t & 1023, r = rem >> 4, xb = rem & 15;
    u32x4 v = *(const u32x4*)&Wcat[(size_t)((r >> 4) * NH + j0 + (r & 15)) * KTOT
                                   + c * 128 + xb * 8];
    *(u32x4*)&BldsH[(c * 64 + r) * 128 + ((xb ^ (r & 15)) << 3)] = v;
  }
  for (int it = 0; it < 5; ++it) {
    int u = tid + it * 256, r = u / 20, iu = u % 20;
    u32x4 v = *(const u32x4*)&Wcat[(size_t)((r >> 4) * NH + j0 + (r & 15)) * KTOT
                                   + 1024 + iu * 8];
    *(u32x4*)&BldsX[r * LSTR + iu * 8] = v;
  }
  __syncthreads();

  // ---- per-lane addressing ----
  // A: two 16-row batch tiles per wave (a=0,1), rows b0+bh*32+a*16+cl
  const size_t aB0 = (size_t)(b0 + bh * 32 + cl) * NH + quad * 8;
  const size_t aB1 = aB0 + (size_t)16 * NH;
  const size_t axB0 = (size_t)(b0 + bh * 32 + cl) * NPPAD + quad * 8;
  const size_t axB1 = axB0 + (size_t)16 * NPPAD;
  // B rows for this lane: tile0 -> gates {0,1}, tile1 -> gates {2,3}
  const int swzk  = jh * 8 + (cl & 7);            // == row & 15 for both tiles
  const int rowB0 = ((cl >> 3) * 16) + swzk;
  const int rowB1 = rowB0 + 32;

  u32x4 A0[8], A1[8], A2[8], AX[10];   // 3 rotating 8-load sets (depth 2)
  uint32_t f2 = 0, f3 = 0, f4 = 0, f5 = 0, f6 = 0, f7 = 0;
  f32x4 acc[2][2];                     // [A-tile][B-tile]
  float cst[4];                        // c-state: (a, row-pair) per lane
  #pragma unroll
  for (int r = 0; r < 4; ++r) cst[r] = 0.f;

#define FLAGP(ch) (&bar[(bb * 8 + (ch)) * 32])
#define ISSUE_AH(SET, HP, chn) do { \
    const bf16* g0_ = (HP) + aB0 + (chn) * 128; \
    const bf16* g1_ = (HP) + aB1 + (chn) * 128; \
    SET[0] = ld16sel(g0_, DEEP);      SET[1] = ld16sel(g0_ + 32, DEEP); \
    SET[2] = ld16sel(g0_ + 64, DEEP); SET[3] = ld16sel(g0_ + 96, DEEP); \
    SET[4] = ld16sel(g1_, DEEP);      SET[5] = ld16sel(g1_ + 32, DEEP); \
    SET[6] = ld16sel(g1_ + 64, DEEP); SET[7] = ld16sel(g1_ + 96, DEEP); } while (0)
#define ISSUE_AX(sv) do { \
    const bf16* g0_ = X + (size_t)(sv) * NB * NPPAD + axB0; \
    const bf16* g1_ = X + (size_t)(sv) * NB * NPPAD + axB1; \
    if ((sv) < 120) { \
      _Pragma("unroll") \
      for (int ks_ = 0; ks_ < 5; ++ks_) { AX[ks_] = g_ld16(g0_ + ks_ * 32); \
                                          AX[5 + ks_] = g_ld16(g1_ + ks_ * 32); } \
    } else { \
      _Pragma("unroll") \
      for (int ks_ = 0; ks_ < 5; ++ks_) { AX[ks_] = ld16sel(g0_ + ks_ * 32, DEEP); \
                                          AX[5 + ks_] = ld16sel(g1_ + ks_ * 32, DEEP); } \
    } } while (0)
// one B-frag pair read per ks, shared by both A-tiles: 8 reads, 16 MFMAs
#define MFMA_LDS(SET, c) do { \
    _Pragma("unroll") \
    for (int ks = 0; ks < 4; ++ks) { \
      int slot_ = (((ks * 4 + quad) ^ swzk) << 3); \
      bf16x8 b0_ = *(const bf16x8*)&BldsH[((c) * 64 + rowB0) * 128 + slot_]; \
      bf16x8 b1_ = *(const bf16x8*)&BldsH[((c) * 64 + rowB1) * 128 + slot_]; \
      bf16x8 a0_ = __builtin_bit_cast(bf16x8, SET[ks]); \
      bf16x8 a1_ = __builtin_bit_cast(bf16x8, SET[4 + ks]); \
      acc[0][0] = __builtin_amdgcn_mfma_f32_16x16x32_bf16(a0_, b0_, acc[0][0], 0, 0, 0); \
      acc[0][1] = __builtin_amdgcn_mfma_f32_16x16x32_bf16(a0_, b1_, acc[0][1], 0, 0, 0); \
      acc[1][0] = __builtin_amdgcn_mfma_f32_16x16x32_bf16(a1_, b0_, acc[1][0], 0, 0, 0); \
      acc[1][1] = __builtin_amdgcn_mfma_f32_16x16x32_bf16(a1_, b1_, acc[1][1], 0, 0, 0); \
    } } while (0)
#define MFMA_X() do { \
    _Pragma("unroll") \
    for (int ks = 0; ks < 5; ++ks) { \
      bf16x8 b0_ = *(const bf16x8*)&BldsX[rowB0 * LSTR + ks * 32 + quad * 8]; \
      bf16x8 b1_ = *(const bf16x8*)&BldsX[rowB1 * LSTR + ks * 32 + quad * 8]; \
      bf16x8 a0_ = __builtin_bit_cast(bf16x8, AX[ks]); \
      bf16x8 a1_ = __builtin_bit_cast(bf16x8, AX[5 + ks]); \
      acc[0][0] = __builtin_amdgcn_mfma_f32_16x16x32_bf16(a0_, b0_, acc[0][0], 0, 0, 0); \
      acc[0][1] = __builtin_amdgcn_mfma_f32_16x16x32_bf16(a0_, b1_, acc[0][1], 0, 0, 0); \
      acc[1][0] = __builtin_amdgcn_mfma_f32_16x16x32_bf16(a1_, b0_, acc[1][0], 0, 0, 0); \
      acc[1][1] = __builtin_amdgcn_mfma_f32_16x16x32_bf16(a1_, b1_, acc[1][1], 0, 0, 0); \
    } } while (0)

  // ---- prologue: chunks 0,1 of step 0 (FIFO: A0,F2,A1,F3 = 18 outstanding) ----
  ISSUE_AH(A0, H, 0);  f2 = llc_ld4(FLAGP(2));
  ISSUE_AH(A1, H, 1);  f3 = llc_ld4(FLAGP(3));

  for (int s = 0; s < NSTEPS; ++s) {
    const bf16* Hr = H + (size_t)(DEEP ? s : (s & 1)) * (NB * NH);
    bf16* Hw = H + (size_t)(DEEP ? (s + 1) : ((s + 1) & 1)) * (NB * NH);
    #pragma unroll
    for (int a = 0; a < 2; ++a)
      #pragma unroll
      for (int bt = 0; bt < 2; ++bt) acc[a][bt] = f32x4{0, 0, 0, 0};
    const int tgt = 8 * s;    // h(s) chunk-ready target
    bool drained = false;

    // Ledger (FIFO), 8-load sets: entry [A0c0(8),F2,A1c1(8),F3] = 18.
    WAIT_VM(9);  CHKD(f2, 2, tgt); ISSUE_AH(A2, Hr, 2); f4 = llc_ld4(FLAGP(4)); MFMA_LDS(A0, 0);
    WAIT_VMC(9); CHKD(f3, 3, tgt); ISSUE_AH(A0, Hr, 3); f5 = llc_ld4(FLAGP(5)); MFMA_LDS(A1, 1);
    WAIT_VMC(9); CHKD(f4, 4, tgt); ISSUE_AH(A1, Hr, 4); f6 = llc_ld4(FLAGP(6)); MFMA_LDS(A2, 2);
    WAIT_VMC(9); CHKD(f5, 5, tgt); ISSUE_AH(A2, Hr, 5); f7 = llc_ld4(FLAGP(7)); MFMA_LDS(A0, 3);
    WAIT_VMC(9); CHKD(f6, 6, tgt); ISSUE_AH(A0, Hr, 6);                         MFMA_LDS(A1, 4);
    WAIT_VMC(8); CHKD(f7, 7, tgt); ISSUE_AH(A1, Hr, 7);                         MFMA_LDS(A2, 5);
    WAIT_VMC(8);
    if (s >= 120) POLL(&bar[(32 + bb) * 32], 4 * (s - 119));   // decoder X gate
    ISSUE_AX(s);                                               MFMA_LDS(A0, 6);
    WAIT_VMC(10);                                              MFMA_LDS(A1, 7);
    WAIT_VMC(0);                                               MFMA_X();

    // ---- gate merge (pairs cl, cl^8) + activations + h-store + flag ----
    // tile0 cols: lanes cl<8 hold i, cl>=8 hold f; tile1: g / o.
    // lo lane computes rows quad*4+{0,1}; hi lane rows quad*4+{2,3}.
    {
      const bool hi = (cl & 8) != 0;
      #pragma unroll
      for (int a = 0; a < 2; ++a) {
        float s0[4], s1[4];
        #pragma unroll
        for (int e = 0; e < 4; ++e) {
          s0[e] = __shfl_xor(acc[a][0][e], 8);
          s1[e] = __shfl_xor(acc[a][1][e], 8);
        }
        #pragma unroll
        for (int rr = 0; rr < 2; ++rr) {
          int r = hi ? (2 + rr) : rr;
          float iv = hi ? s0[r] : acc[a][0][r];
          float fv = hi ? acc[a][0][r] : s0[r];
          float gv = hi ? s1[r] : acc[a][1][r];
          float ov = hi ? acc[a][1][r] : s1[r];
          float cn = sigm(fv) * cst[a * 2 + rr] + sigm(iv) * tanh_(gv);
          cst[a * 2 + rr] = cn;
          float h = sigm(ov) * tanh_(cn);
          bf16 hb = (bf16)h;
          llc_st2(&Hw[(size_t)(b0 + bh * 32 + a * 16 + quad * 4 + r) * NH
                      + j0 + jh * 8 + (cl & 7)],
                  (uint32_t)__builtin_bit_cast(uint16_t, hb));
        }
      }
    }
    WAIT_VM(0);                                     // h-tile acked at LLC
    __syncthreads();                                // all 4 waves stored
    if (tid == 0) atomicAdd(&bar[(bb * 8 + mych) * 32], 1);

    if (s >= 119 && is_out) {   // decoder: out = inp + h_new @ W_fc^T + b_fc
      const int k = s - 119;
      POLL_ALL8(8 * (s + 1));                       // full h(s+1) ready
      f32x4 oa[3] = {{0,0,0,0},{0,0,0,0},{0,0,0,0}};
      const bf16* hrow = Hw + (size_t)(brow0 + cl) * NH;
      for (int kb = 0; kb < 4; ++kb) {
        u32x4 hv[8];
        #pragma unroll
        for (int t = 0; t < 8; ++t)
          hv[t] = ld16sel(&hrow[(kb * 8 + t) * 32 + quad * 8], DEEP);
        WAIT_VM(0);
        #pragma unroll
        for (int t = 0; t < 8; ++t) {
          bf16x8 af = __builtin_bit_cast(bf16x8, hv[t]);
          #pragma unroll
          for (int i = 0; i < 3; ++i) {
            int ct = wv + i * 4;
            if (ct > 8) continue;
            bf16x8 bw = *(const bf16x8*)&Wfcb[(size_t)(ct * 16 + cl) * NH
                                              + (kb * 8 + t) * 32 + quad * 8];
            oa[i] = __builtin_amdgcn_mfma_f32_16x16x32_bf16(af, bw, oa[i], 0, 0, 0);
          }
        }
      }
      #pragma unroll
      for (int i = 0; i < 3; ++i) {
        int ct = wv + i * 4;
        if (ct > 8) continue;
        int p = ct * 16 + cl;
        if (p < NPOSE) {
          #pragma unroll
          for (int r = 0; r < 4; ++r) {
            int b = brow0 + quad * 4 + r;
            float inp = (k == 0) ? poses[((size_t)b * 144 + 119) * NPOSE + p]
                                 : out[((size_t)b * NDEC + (k - 1)) * NPOSE + p];
            float v = oa[i][r] + inp + bfc[p];       // additive chain kept fp32
            out[((size_t)b * NDEC + k) * NPOSE + p] = v;
            if (s + 1 < NSTEPS) {
              bf16 xb = (bf16)v;
              llc_st2(&X[((size_t)(s + 1) * NB + b) * NPPAD + p],
                      (uint32_t)__builtin_bit_cast(uint16_t, xb));
            }
          }
        }
      }
      if (s + 1 < NSTEPS) {
        WAIT_VM(0);                                 // X(s+1) acked at LLC
        __syncthreads();
        if (tid == 0) atomicAdd(&bar[(32 + bb) * 32], 1);
      }
    }

    // ---- tail: gate chunks 0,1 (DEEP: write-once slots -> no WAR);
    //      fallback keeps the all-8 gate. Issue 2 sets + F2,F3 (entry=18). ----
    if (s + 1 < NSTEPS) {
      if constexpr (DEEP) { POLL01(8 * (s + 1)); }
      else                { POLL_ALL8(8 * (s + 1)); }
      ISSUE_AH(A0, Hw, 0);  f2 = llc_ld4(FLAGP(2));
      ISSUE_AH(A1, Hw, 1);  f3 = llc_ld4(FLAGP(3));
    }
  }
}

extern "C" void kernel_launch(void* const* d_in, const int* in_sizes, int n_in,
                              void* d_out, int out_size, void* d_ws, size_t ws_size,
                              hipStream_t stream) {
  const float* poses = (const float*)d_in[0];
  const float* Wih   = (const float*)d_in[1];
  const float* Whh   = (const float*)d_in[2];
  const float* Wfc   = (const float*)d_in[3];
  const float* bfc   = (const float*)d_in[4];

  const size_t need_deep = (size_t)H_OFF + H_BYTES144 + BAR_BYTES;
  const size_t need_min  = (size_t)H_OFF + H_BYTES2 + BAR_BYTES;
  if (ws_size < need_min) return;
  const bool deep = ws_size >= need_deep;
  const size_t hbytes = deep ? (size_t)H_BYTES144 : (size_t)H_BYTES2;

  char* ws = (char*)d_ws;
  bf16* Wcat = (bf16*)(ws + WCAT_OFF);
  bf16* Wfcb = (bf16*)(ws + WFC_OFF);
  bf16* X    = (bf16*)(ws + X_OFF);
  bf16* H    = (bf16*)(ws + H_OFF);
  int*  bar  = (int*)(ws + H_OFF + hbytes);

  if (deep) {
    k_zero<<<256, 256, 0, stream>>>((uint32_t*)(ws + H_OFF), (int)(NB * NH * 2 / 4));
    k_zero<<<32, 256, 0, stream>>>((uint32_t*)bar, BAR_BYTES / 4);
  } else {
    k_zero<<<256, 256, 0, stream>>>((uint32_t*)(ws + H_OFF),
                                    (int)((H_BYTES2 + BAR_BYTES) / 4));
  }
  k_zero<<<256, 256, 0, stream>>>((uint32_t*)(X + (size_t)120 * NB * NPPAD),
                                  (int)(23l * NB * NPPAD * 2 / 4));
  k_wcat<<<4096, 256, 0, stream>>>(Whh, Wih, Wcat);
  k_wfc<<<144, 256, 0, stream>>>(Wfc, Wfcb);
  k_x<<<120 * 256, 256, 0, stream>>>(poses, X);
  if (deep)
    k_main<true><<<NWG, 256, 0, stream>>>(poses, bfc, Wcat, Wfcb, X, H, bar,
                                          (float*)d_out);
  else
    k_main<false><<<NWG, 256, 0, stream>>>(poses, bfc, Wcat, Wfcb, X, H, bar,
                                           (float*)d_out);
}

// Round 18
// 1563.489 us; speedup vs baseline: 1.3405x; 1.3405x over previous
//
#include <hip/hip_runtime.h>
#include <stdint.h>

#define NB 256          // batch
#define NH 1024         // hidden
#define NPOSE 135
#define NPPAD 160       // pose padded to 160
#define NSTEPS 143      // 119 encoder + 24 decoder cell steps
#define NDEC 24
#define KTOT 1184       // 1024 (h) + 160 (x padded)
#define LSTR 168        // LDS row stride for x-B chunk
#define NWG 256

typedef __bf16 bf16;
typedef __attribute__((ext_vector_type(8))) __bf16 bf16x8;
typedef __attribute__((ext_vector_type(4))) float f32x4;
typedef __attribute__((ext_vector_type(4))) uint32_t u32x4;

// ---- ws layout (bytes) ----
#define WCAT_OFF 0
#define WCAT_BYTES (4096l * KTOT * 2)
#define WFC_OFF  (WCAT_OFF + WCAT_BYTES)
#define WFC_BYTES (144l * 1024 * 2)
#define X_OFF    (WFC_OFF + WFC_BYTES)
#define X_BYTES  (143l * NB * NPPAD * 2)
#define H_OFF    (X_OFF + X_BYTES)
#define H_BYTES2    (2l * NB * NH * 2)     // fallback: ping-pong
#define H_BYTES144  (144l * NB * NH * 2)   // deep: slot per step -> cacheable
#define BAR_BYTES 16384
// bar ints, one counter per 128B line:
//   cnt[bb][ch] at bar[(bb*8+ch)*32]  (h-chunk ready; 8 producers, +8/step)
//   xcnt[bb]    at bar[(32+bb)*32]    (decoder X ready; +4/out-step)

__device__ __forceinline__ u32x4 llc_ld16(const void* p) {
  u32x4 v;
  asm volatile("global_load_dwordx4 %0, %1, off sc0 sc1"
               : "=v"(v) : "v"(p) : "memory");
  return v;
}
__device__ __forceinline__ uint32_t llc_ld4(const void* p) {   // pipelined flag load
  uint32_t v;
  asm volatile("global_load_dword %0, %1, off sc0 sc1"
               : "=v"(v) : "v"(p) : "memory");
  return v;
}
__device__ __forceinline__ u32x4 g_ld16(const void* p) {   // cached
  u32x4 v;
  asm volatile("global_load_dwordx4 %0, %1, off"
               : "=v"(v) : "v"(p) : "memory");
  return v;
}
__device__ __forceinline__ u32x4 ld16sel(const void* p, bool cached) {
  return cached ? g_ld16(p) : llc_ld16(p);
}
__device__ __forceinline__ void llc_st2(void* p, uint32_t v) {
  asm volatile("global_store_short %0, %1, off sc0 sc1"
               :: "v"(p), "v"(v) : "memory");
}
#define WAIT_VM(n) do { \
    asm volatile("s_waitcnt vmcnt(" #n ")" ::: "memory"); \
    __builtin_amdgcn_sched_barrier(0); } while (0)
// counted wait that degrades to a full drain after a CHK slow path (the
// drain breaks counted-wait/set alignment -> conservative for rest of step)
#define WAIT_VMC(n) do { \
    if (__builtin_expect(drained, 0)) { WAIT_VM(0); } else { WAIT_VM(n); } } while (0)

// Blocking polls force vmcnt(0) (newest-load rule): allowed only at tail /
// decoder / slow path. Fast-path chunk gating uses PIPELINED flag loads that
// retire through the normal phase WAIT_VM ledger (zero extra stalls).
#define POLL(ptr, tgt) do { \
    while (__hip_atomic_load((ptr), __ATOMIC_RELAXED, __HIP_MEMORY_SCOPE_AGENT) < (tgt)) \
      __builtin_amdgcn_s_sleep(1); \
  } while (0)
#define POLL_ALL8(tgt) do { \
    for (;;) { \
      int v_ = __hip_atomic_load(&bar[(bb * 8 + (lane & 7)) * 32], \
                                 __ATOMIC_RELAXED, __HIP_MEMORY_SCOPE_AGENT); \
      if (__all(v_ >= (tgt))) break; \
      __builtin_amdgcn_s_sleep(1); \
    } } while (0)
#define POLL012(tgt) do { \
    int c_ = lane & 3; c_ = (c_ == 3) ? 0 : c_; \
    for (;;) { \
      int v_ = __hip_atomic_load(&bar[(bb * 8 + c_) * 32], \
                                 __ATOMIC_RELAXED, __HIP_MEMORY_SCOPE_AGENT); \
      if (__all(v_ >= (tgt))) break; \
      __builtin_amdgcn_s_sleep(1); \
    } } while (0)
// fast-path check of a pipelined flag value; slow path re-loads with full
// drain (rare: producer genuinely late) and flags the step as drained.
#define CHKD(fv, ch, tgt) do { \
    while ((int)(fv) < (tgt)) { \
      drained = true; \
      __builtin_amdgcn_s_sleep(1); \
      fv = llc_ld4(&bar[(bb * 8 + (ch)) * 32]); \
      WAIT_VM(0); \
    } } while (0)

__global__ void k_zero(uint32_t* p, int n) {
  int i = blockIdx.x * blockDim.x + threadIdx.x;
  int st = gridDim.x * blockDim.x;
  for (; i < n; i += st) p[i] = 0u;
}

__global__ void k_wcat(const float* __restrict__ Whh, const float* __restrict__ Wih,
                       bf16* __restrict__ W) {
  int n = blockIdx.x;
  for (int kk = threadIdx.x; kk < KTOT; kk += blockDim.x) {
    float v = 0.f;
    if (kk < NH) v = Whh[(size_t)n * NH + kk];
    else if (kk - NH < NPOSE) v = Wih[(size_t)n * NPOSE + (kk - NH)];
    W[(size_t)n * KTOT + kk] = (bf16)v;
  }
}

__global__ void k_wfc(const float* __restrict__ Wfc, bf16* __restrict__ W) {
  int p = blockIdx.x;
  for (int kk = threadIdx.x; kk < NH; kk += blockDim.x) {
    float v = (p < NPOSE) ? Wfc[(size_t)p * NH + kk] : 0.f;
    W[(size_t)p * NH + kk] = (bf16)v;
  }
}

__global__ void k_x(const float* __restrict__ poses, bf16* __restrict__ X) {
  int idx = blockIdx.x;          // t*256 + b, t in [0,120)
  int t = idx >> 8, b = idx & 255;
  int p = threadIdx.x;
  if (p < NPPAD) {
    float v = (p < NPOSE) ? poses[((size_t)b * 144 + t) * NPOSE + p] : 0.f;
    X[(size_t)idx * NPPAD + p] = (bf16)v;
  }
}

__device__ __forceinline__ float sigm(float x) { return 1.f / (1.f + __expf(-x)); }
__device__ __forceinline__ float tanh_(float x) {
  float e = __expf(2.f * x);
  return 1.f - 2.f / (e + 1.f);
}

template <bool DEEP>
__global__ __launch_bounds__(256, 1) void
k_main(const float* __restrict__ poses, const float* __restrict__ bfc,
       const bf16* __restrict__ Wcat, const bf16* __restrict__ Wfcb,
       bf16* __restrict__ X, bf16* __restrict__ H, int* __restrict__ bar,
       float* __restrict__ out) {
  // W staged to LDS once (r7/r9 layout):
  // BldsH[c][r = gate*16 + j][k], 16B-group e stored at slot e ^ (r&15).
  __shared__ bf16 BldsH[8 * 64 * 128];     // 128 KiB
  __shared__ bf16 BldsX[64 * LSTR];        // 21 KiB

  const int tid  = threadIdx.x;
  const int lane = tid & 63;
  const int wv   = tid >> 6;
  const int cl   = lane & 15;
  const int quad = lane >> 4;
  const int L    = blockIdx.x;
  const int jb = (L & 7) * 8 + ((L >> 3) & 7);   // XCD-aware j-block
  const int bb = L >> 6;                          // batch group
  const int b0 = bb * 64;
  const int j0 = jb * 16;
  const int mych = jb >> 3;                       // h-chunk this WG produces
  const bool is_out = ((L & 7) == 7) && (((L >> 3) & 7) < 4);
  const int brow0 = bb * 64 + ((L >> 3) & 7) * 16;

  // ---- one-time B staging (plain loads; compiler-managed waits) ----
  for (int t = tid; t < 8 * 64 * 16; t += 256) {
    int c = t >> 10, rem = t & 1023, r = rem >> 4, xb = rem & 15;
    u32x4 v = *(const u32x4*)&Wcat[(size_t)((r >> 4) * NH + j0 + (r & 15)) * KTOT
                                   + c * 128 + xb * 8];
    *(u32x4*)&BldsH[(c * 64 + r) * 128 + ((xb ^ (r & 15)) << 3)] = v;
  }
  for (int it = 0; it < 5; ++it) {
    int u = tid + it * 256, r = u / 20, iu = u % 20;
    u32x4 v = *(const u32x4*)&Wcat[(size_t)((r >> 4) * NH + j0 + (r & 15)) * KTOT
                                   + 1024 + iu * 8];
    *(u32x4*)&BldsX[r * LSTR + iu * 8] = v;
  }
  __syncthreads();

  // ---- per-lane A addressing (direct-to-fragment; A never touches LDS) ----
  const int arow = b0 + wv * 16 + cl;                 // A row this lane owns
  const size_t aBase  = (size_t)arow * NH + quad * 8;
  const size_t axBase = (size_t)arow * NPPAD + quad * 8;

  u32x4 A0[4], A1[4], A2[4], A3[4], AX[5];   // 4 rotating sets (depth 3)
  uint32_t f3 = 0, f4 = 0, f5 = 0, f6 = 0, f7 = 0;
  f32x4 acc[4];
  float cst[4] = {0.f, 0.f, 0.f, 0.f};

#define FLAGP(ch) (&bar[(bb * 8 + (ch)) * 32])
#define ISSUE_AH(SET, HP, chn) do { \
    const bf16* ga_ = (HP) + aBase + (chn) * 128; \
    SET[0] = ld16sel(ga_, DEEP);      SET[1] = ld16sel(ga_ + 32, DEEP); \
    SET[2] = ld16sel(ga_ + 64, DEEP); SET[3] = ld16sel(ga_ + 96, DEEP); } while (0)
#define ISSUE_AX(sv) do { \
    const bf16* ga_ = X + (size_t)(sv) * NB * NPPAD + axBase; \
    if ((sv) < 120) { \
      AX[0] = g_ld16(ga_);        AX[1] = g_ld16(ga_ + 32); \
      AX[2] = g_ld16(ga_ + 64);   AX[3] = g_ld16(ga_ + 96); \
      AX[4] = g_ld16(ga_ + 128); \
    } else { \
      AX[0] = ld16sel(ga_, DEEP);       AX[1] = ld16sel(ga_ + 32, DEEP); \
      AX[2] = ld16sel(ga_ + 64, DEEP);  AX[3] = ld16sel(ga_ + 96, DEEP); \
      AX[4] = ld16sel(ga_ + 128, DEEP); \
    } } while (0)
#define MFMA_LDS(SET, c) do { \
    _Pragma("unroll") \
    for (int ks = 0; ks < 4; ++ks) { \
      bf16x8 af_ = __builtin_bit_cast(bf16x8, SET[ks]); \
      _Pragma("unroll") \
      for (int gb = 0; gb < 4; ++gb) { \
        bf16x8 bw_ = *(const bf16x8*)&BldsH[((c) * 64 + gb * 16 + cl) * 128 \
                                            + (((ks * 4 + quad) ^ cl) << 3)]; \
        acc[gb] = __builtin_amdgcn_mfma_f32_16x16x32_bf16(af_, bw_, acc[gb], 0, 0, 0); \
      } } } while (0)
#define MFMA_X() do { \
    _Pragma("unroll") \
    for (int ks = 0; ks < 5; ++ks) { \
      bf16x8 af_ = __builtin_bit_cast(bf16x8, AX[ks]); \
      _Pragma("unroll") \
      for (int gb = 0; gb < 4; ++gb) { \
        bf16x8 bw_ = *(const bf16x8*)&BldsX[(gb * 16 + cl) * LSTR + ks * 32 + quad * 8]; \
        acc[gb] = __builtin_amdgcn_mfma_f32_16x16x32_bf16(af_, bw_, acc[gb], 0, 0, 0); \
      } } } while (0)

  // ---- prologue: step 0 (h(0)=zeros, flags 0 -> targets 0 pass trivially).
  // FIFO issue order A0,F3,A1,F4,A2,F5 = 15 outstanding (ledger contract).
  ISSUE_AH(A0, H, 0);  f3 = llc_ld4(FLAGP(3));
  ISSUE_AH(A1, H, 1);  f4 = llc_ld4(FLAGP(4));
  ISSUE_AH(A2, H, 2);  f5 = llc_ld4(FLAGP(5));

  for (int s = 0; s < NSTEPS; ++s) {
    const bf16* Hr = H + (size_t)(DEEP ? s : (s & 1)) * (NB * NH);
    bf16* Hw = H + (size_t)(DEEP ? (s + 1) : ((s + 1) & 1)) * (NB * NH);
    #pragma unroll
    for (int gb = 0; gb < 4; ++gb) acc[gb] = f32x4{0, 0, 0, 0};
    const int tgt = 8 * s;    // h(s) chunk-ready target
    bool drained = false;

    // Depth-3 ledger (FIFO): entry [A0(4),F3,A1(4),F4,A2(4),F5] = 15.
    // Set consumed at phase p was issued at phase p-3 (~3 phases of lookahead).
    WAIT_VM(10);  CHKD(f3, 3, tgt); ISSUE_AH(A3, Hr, 3); f6 = llc_ld4(FLAGP(6)); MFMA_LDS(A0, 0);
    WAIT_VMC(10); CHKD(f4, 4, tgt); ISSUE_AH(A0, Hr, 4); f7 = llc_ld4(FLAGP(7)); MFMA_LDS(A1, 1);
    WAIT_VMC(10); CHKD(f5, 5, tgt); ISSUE_AH(A1, Hr, 5);                         MFMA_LDS(A2, 2);
    WAIT_VMC(9);  CHKD(f6, 6, tgt); ISSUE_AH(A2, Hr, 6);                         MFMA_LDS(A3, 3);
    WAIT_VMC(8);  CHKD(f7, 7, tgt); ISSUE_AH(A3, Hr, 7);                         MFMA_LDS(A0, 4);
    WAIT_VMC(8);
    if (s >= 120) POLL(&bar[(32 + bb) * 32], 4 * (s - 119));   // decoder X gate
    ISSUE_AX(s);                                               MFMA_LDS(A1, 5);
    WAIT_VMC(9);                                               MFMA_LDS(A2, 6);
    WAIT_VMC(5);                                               MFMA_LDS(A3, 7);
    WAIT_VMC(0);                                               MFMA_X();

    // ---- activations + h-store (write-through) + ready signal ----
    #pragma unroll
    for (int r = 0; r < 4; ++r) {
      float gi = sigm(acc[0][r]);
      float gf = sigm(acc[1][r]);
      float gg = tanh_(acc[2][r]);
      float go = sigm(acc[3][r]);
      float cn = gf * cst[r] + gi * gg;
      cst[r] = cn;
      float h = go * tanh_(cn);
      bf16 hb = (bf16)h;
      llc_st2(&Hw[(size_t)(b0 + wv * 16 + quad * 4 + r) * NH + j0 + cl],
              (uint32_t)__builtin_bit_cast(uint16_t, hb));
    }
    WAIT_VM(0);                                     // h-tile acked at LLC
    __syncthreads();                                // all 4 waves stored
    if (tid == 0) atomicAdd(&bar[(bb * 8 + mych) * 32], 1);

    if (s >= 119 && is_out) {   // decoder: out = inp + h_new @ W_fc^T + b_fc
      const int k = s - 119;
      POLL_ALL8(8 * (s + 1));                       // full h(s+1) ready
      f32x4 oa[3] = {{0,0,0,0},{0,0,0,0},{0,0,0,0}};
      const bf16* hrow = Hw + (size_t)(brow0 + cl) * NH;
      for (int kb = 0; kb < 4; ++kb) {
        u32x4 hv[8];
        #pragma unroll
        for (int t = 0; t < 8; ++t)
          hv[t] = ld16sel(&hrow[(kb * 8 + t) * 32 + quad * 8], DEEP);
        WAIT_VM(0);
        #pragma unroll
        for (int t = 0; t < 8; ++t) {
          bf16x8 af = __builtin_bit_cast(bf16x8, hv[t]);
          #pragma unroll
          for (int i = 0; i < 3; ++i) {
            int ct = wv + i * 4;
            if (ct > 8) continue;
            bf16x8 bw = *(const bf16x8*)&Wfcb[(size_t)(ct * 16 + cl) * NH
                                              + (kb * 8 + t) * 32 + quad * 8];
            oa[i] = __builtin_amdgcn_mfma_f32_16x16x32_bf16(af, bw, oa[i], 0, 0, 0);
          }
        }
      }
      #pragma unroll
      for (int i = 0; i < 3; ++i) {
        int ct = wv + i * 4;
        if (ct > 8) continue;
        int p = ct * 16 + cl;
        if (p < NPOSE) {
          #pragma unroll
          for (int r = 0; r < 4; ++r) {
            int b = brow0 + quad * 4 + r;
            float inp = (k == 0) ? poses[((size_t)b * 144 + 119) * NPOSE + p]
                                 : out[((size_t)b * NDEC + (k - 1)) * NPOSE + p];
            float v = oa[i][r] + inp + bfc[p];       // additive chain kept fp32
            out[((size_t)b * NDEC + k) * NPOSE + p] = v;
            if (s + 1 < NSTEPS) {
              bf16 xb = (bf16)v;
              llc_st2(&X[((size_t)(s + 1) * NB + b) * NPPAD + p],
                      (uint32_t)__builtin_bit_cast(uint16_t, xb));
            }
          }
        }
      }
      if (s + 1 < NSTEPS) {
        WAIT_VM(0);                                 // X(s+1) acked at LLC
        __syncthreads();
        if (tid == 0) atomicAdd(&bar[(32 + bb) * 32], 1);
      }
    }

    // ---- tail: gate chunks 0-2 (DEEP: write-once slots -> no WAR);
    //      fallback keeps the all-8 gate (ping-pong WAR safety). Then issue
    //      3 A-sets + flags F3-F5 for step s+1 (ledger entry = 15). ----
    if (s + 1 < NSTEPS) {
      if constexpr (DEEP) { POLL012(8 * (s + 1)); }
      else                { POLL_ALL8(8 * (s + 1)); }
      ISSUE_AH(A0, Hw, 0);  f3 = llc_ld4(FLAGP(3));
      ISSUE_AH(A1, Hw, 1);  f4 = llc_ld4(FLAGP(4));
      ISSUE_AH(A2, Hw, 2);  f5 = llc_ld4(FLAGP(5));
    }
  }
}

extern "C" void kernel_launch(void* const* d_in, const int* in_sizes, int n_in,
                              void* d_out, int out_size, void* d_ws, size_t ws_size,
                              hipStream_t stream) {
  const float* poses = (const float*)d_in[0];
  const float* Wih   = (const float*)d_in[1];
  const float* Whh   = (const float*)d_in[2];
  const float* Wfc   = (const float*)d_in[3];
  const float* bfc   = (const float*)d_in[4];

  const size_t need_deep = (size_t)H_OFF + H_BYTES144 + BAR_BYTES;
  const size_t need_min  = (size_t)H_OFF + H_BYTES2 + BAR_BYTES;
  if (ws_size < need_min) return;
  const bool deep = ws_size >= need_deep;
  const size_t hbytes = deep ? (size_t)H_BYTES144 : (size_t)H_BYTES2;

  char* ws = (char*)d_ws;
  bf16* Wcat = (bf16*)(ws + WCAT_OFF);
  bf16* Wfcb = (bf16*)(ws + WFC_OFF);
  bf16* X    = (bf16*)(ws + X_OFF);
  bf16* H    = (bf16*)(ws + H_OFF);
  int*  bar  = (int*)(ws + H_OFF + hbytes);

  if (deep) {
    k_zero<<<256, 256, 0, stream>>>((uint32_t*)(ws + H_OFF), (int)(NB * NH * 2 / 4));
    k_zero<<<32, 256, 0, stream>>>((uint32_t*)bar, BAR_BYTES / 4);
  } else {
    k_zero<<<256, 256, 0, stream>>>((uint32_t*)(ws + H_OFF),
                                    (int)((H_BYTES2 + BAR_BYTES) / 4));
  }
  k_zero<<<256, 256, 0, stream>>>((uint32_t*)(X + (size_t)120 * NB * NPPAD),
                                  (int)(23l * NB * NPPAD * 2 / 4));
  k_wcat<<<4096, 256, 0, stream>>>(Whh, Wih, Wcat);
  k_wfc<<<144, 256, 0, stream>>>(Wfc, Wfcb);
  k_x<<<120 * 256, 256, 0, stream>>>(poses, X);
  if (deep)
    k_main<true><<<NWG, 256, 0, stream>>>(poses, bfc, Wcat, Wfcb, X, H, bar,
                                          (float*)d_out);
  else
    k_main<false><<<NWG, 256, 0, stream>>>(poses, bfc, Wcat, Wfcb, X, H, bar,
                                           (float*)d_out);
}